// Round 9
// baseline (151.088 us; speedup 1.0000x reference)
//
#include <hip/hip_runtime.h>
#include <math.h>

typedef unsigned short u16;
typedef unsigned int   u32;
typedef unsigned long long u64;
typedef __attribute__((ext_vector_type(4))) unsigned short u16x4;
typedef __attribute__((ext_vector_type(8))) unsigned short bf16x8;
typedef __attribute__((ext_vector_type(8))) short sh8;      // MFMA A/B frag (8 bf16)
typedef __attribute__((ext_vector_type(4))) float f32x4;    // MFMA C/D frag

#define BT     4096
#define D      2048
#define NC     8
#define NCOL   144     // 64 selW + 64 upd + 8 mu + 8 zero-pad (9 MFMA col-tiles)
#define KSPLIT 16
#define KR     (D / KSPLIT)   // 128

__device__ __forceinline__ float bf2f(u16 v) {
    u32 u = ((u32)v) << 16;
    float f; __builtin_memcpy(&f, &u, 4); return f;
}
__device__ __forceinline__ u16 f2bf(float f) {
    u32 u; __builtin_memcpy(&u, &f, 4);
    u += 0x7fffu + ((u >> 16) & 1);        // RNE
    return (u16)(u >> 16);
}

// ---------------------------------------------------------------------------
// Inline dtype detector (validated R2/R3/R6 A/B): fp32 bit-patterns read as
// bf16 give |v|>1e4 or NaN w.p. ~1; genuine bf16 N(0,1) stays |v|<6.
// Wave-uniform ballot over the same 256 elements -> block-uniform flag.
// ---------------------------------------------------------------------------
__device__ __forceinline__ int detect_fp32(const void* xv) {
    const u16* p = (const u16*)xv;
    int l = threadIdx.x & 63;
    bool bad = false;
#pragma unroll
    for (int i = 0; i < 4; i++) {
        float v = bf2f(p[l * 4 + i]);
        if (!(fabsf(v) < 1e4f)) bad = true;   // catches NaN too
    }
    return __ballot(bad) != 0ull;
}

// ---- dtype-polymorphic loads: DT=0 bf16 buffers, DT=1 fp32 buffers ----
template<int DT> struct IO;
template<> struct IO<0> {
    static __device__ __forceinline__ float ld1(const void* p, size_t i) {
        return bf2f(((const u16*)p)[i]);
    }
    static __device__ __forceinline__ void ld4(const void* p, size_t i, float* o) {
        u16x4 v = *(const u16x4*)((const u16*)p + i);
#pragma unroll
        for (int k = 0; k < 4; k++) o[k] = bf2f(v[k]);
    }
    static __device__ __forceinline__ void ld8(const void* p, size_t i, float* o) {
        bf16x8 v = *(const bf16x8*)((const u16*)p + i);
#pragma unroll
        for (int k = 0; k < 8; k++) o[k] = bf2f(v[k]);
    }
    static __device__ __forceinline__ void st4(void* p, size_t i, const float* v) {
        u16x4 o;
#pragma unroll
        for (int k = 0; k < 4; k++) o[k] = f2bf(v[k]);
        *(u16x4*)((u16*)p + i) = o;
    }
    static __device__ __forceinline__ u16 ldbf(const void* p, size_t i) {
        return ((const u16*)p)[i];
    }
    static __device__ __forceinline__ sh8 afrag(const void* p, size_t i) {
        return *(const sh8*)((const u16*)p + i);
    }
};
template<> struct IO<1> {
    static __device__ __forceinline__ float ld1(const void* p, size_t i) {
        return ((const float*)p)[i];
    }
    static __device__ __forceinline__ void ld4(const void* p, size_t i, float* o) {
        f32x4 a = *(const f32x4*)((const float*)p + i);
#pragma unroll
        for (int k = 0; k < 4; k++) o[k] = a[k];
    }
    static __device__ __forceinline__ void ld8(const void* p, size_t i, float* o) {
        f32x4 a = *(const f32x4*)((const float*)p + i);
        f32x4 b = *(const f32x4*)((const float*)p + i + 4);
#pragma unroll
        for (int k = 0; k < 4; k++) { o[k] = a[k]; o[4 + k] = b[k]; }
    }
    static __device__ __forceinline__ void st4(void* p, size_t i, const float* v) {
        f32x4 a;
#pragma unroll
        for (int k = 0; k < 4; k++) a[k] = v[k];
        *(f32x4*)((float*)p + i) = a;
    }
    static __device__ __forceinline__ u16 ldbf(const void* p, size_t i) {
        return f2bf(((const float*)p)[i]);
    }
    static __device__ __forceinline__ sh8 afrag(const void* p, size_t i) {
        f32x4 a = *(const f32x4*)((const float*)p + i);
        f32x4 b = *(const f32x4*)((const float*)p + i + 4);
        sh8 r;
#pragma unroll
        for (int k = 0; k < 4; k++) {
            r[k]     = (short)f2bf(a[k]);
            r[4 + k] = (short)f2bf(b[k]);
        }
        return r;
    }
};

// ---------------------------------------------------------------------------
// k_prep (216 blocks):
//  0..143 : WtT bf16 [144][2048] (B^T): rows 0..63 selW[n][:,s],
//           64..127 upd[n][:,h], 128..135 mu[n], 136..143 zeros
//  144..151: per-concept consts off/mu2/ub — one block per concept, direct
//            writes (NO atomics -> no memset node needed)
//  152..215: DGN -> bf16 repack
// ---------------------------------------------------------------------------
template<int DT>
__device__ __forceinline__ void prep_part(const void* selW, const void* upd,
                                          const void* mu, u16* __restrict__ WtT) {
    int idx = blockIdx.x * 256 + threadIdx.x;
    int j = idx >> 8, d0 = (idx & 255) * 8;
    bf16x8 v;
    if (j < 64) {
        int n = j >> 3, s = j & 7;
#pragma unroll
        for (int i = 0; i < 8; i++) v[i] = IO<DT>::ldbf(selW, ((size_t)n * D + d0 + i) * 8 + s);
    } else if (j < 128) {
        int n = (j - 64) >> 3, h = j & 7;
#pragma unroll
        for (int i = 0; i < 8; i++) v[i] = IO<DT>::ldbf(upd, ((size_t)n * D + d0 + i) * 8 + h);
    } else if (j < 136) {
#pragma unroll
        for (int i = 0; i < 8; i++) v[i] = IO<DT>::ldbf(mu, (size_t)(j - 128) * D + d0 + i);
    } else {
#pragma unroll
        for (int i = 0; i < 8; i++) v[i] = 0;
    }
    *(bf16x8*)(WtT + (size_t)j * D + d0) = v;
}

template<int DT>
__device__ __forceinline__ void consts_part(const void* W, const void* mu,
                                            const void* upd, const void* deb,
                                            float* gOff, float* gMu2, float* gUb) {
    int n = blockIdx.x - 144, t = threadIdx.x;
    float o[8] = {}, u[8] = {};
    float m2 = 0.f;
    for (int d = t; d < D; d += 256) {
        float mud = IO<DT>::ld1(mu,  (size_t)n * D + d);
        float dbd = IO<DT>::ld1(deb, (size_t)n * D + d);
        m2 += mud * mud;
        float wv[8], uv[8];
        IO<DT>::ld8(W,   ((size_t)n * D + d) * 8, wv);
        IO<DT>::ld8(upd, ((size_t)n * D + d) * 8, uv);
#pragma unroll
        for (int s = 0; s < 8; s++) {
            o[s] += wv[s] * mud;
            u[s] += uv[s] * dbd;
        }
    }
#pragma unroll
    for (int i = 1; i < 64; i <<= 1) {
        m2 += __shfl_xor(m2, i, 64);
#pragma unroll
        for (int s = 0; s < 8; s++) {
            o[s] += __shfl_xor(o[s], i, 64);
            u[s] += __shfl_xor(u[s], i, 64);
        }
    }
    __shared__ float red[4][17];
    int wave = t >> 6, lane = t & 63;
    if (lane == 0) {
        red[wave][0] = m2;
#pragma unroll
        for (int s = 0; s < 8; s++) { red[wave][1 + s] = o[s]; red[wave][9 + s] = u[s]; }
    }
    __syncthreads();
    if (t == 0) {
        float acc[17];
#pragma unroll
        for (int i = 0; i < 17; i++)
            acc[i] = red[0][i] + red[1][i] + red[2][i] + red[3][i];
        gMu2[n] = acc[0];
#pragma unroll
        for (int s = 0; s < 8; s++) { gOff[n * 8 + s] = acc[1 + s]; gUb[n * 8 + s] = acc[9 + s]; }
    }
}

template<int DT>
__device__ __forceinline__ void dgnb_part(const void* dgn, u16* __restrict__ dgnb) {
    int idx = (blockIdx.x - 152) * 256 + threadIdx.x;   // 16384 threads x 8 elems
    float v[8];
    IO<DT>::ld8(dgn, (size_t)idx * 8, v);
    bf16x8 o;
#pragma unroll
    for (int k = 0; k < 8; k++) o[k] = f2bf(v[k]);
    *(bf16x8*)(dgnb + (size_t)idx * 8) = o;
}

__global__ __launch_bounds__(256) void k_prep(
    const void* x, const void* selW, const void* upd, const void* mu,
    const void* deb, const void* dgn, u16* WtT,
    float* gOff, float* gMu2, float* gUb, u16* dgnb) {
    int f = detect_fp32(x);
    if (blockIdx.x < 144) {
        if (f) prep_part<1>(selW, upd, mu, WtT); else prep_part<0>(selW, upd, mu, WtT);
    } else if (blockIdx.x < 152) {
        if (f) consts_part<1>(selW, mu, upd, deb, gOff, gMu2, gUb);
        else   consts_part<0>(selW, mu, upd, deb, gOff, gMu2, gUb);
    } else {
        if (f) dgnb_part<1>(dgn, dgnb); else dgnb_part<0>(dgn, dgnb);
    }
}

// ---------------------------------------------------------------------------
// k_gemm: Pb[p][tok][144] (bf16) = X[:, p*128:(p+1)*128] * WtT^T via
// bf16 MFMA 16x16x32; per-slice Σx² (fp32). Grid (64,16) = 1024 blocks,
// 4 waves each -> 4 waves/SIMD (2x R7). PLAIN stores only. bf16 slices
// halve P bytes; error contribution ~2e-4 on output (threshold 8.8e-3).
// A-frag: lane l holds X[tok0+(l&15)][k0+(l>>4)*8..+8] (fp32->bf16 in-reg)
// C/D: row(token) = (l>>4)*4 + reg, col = l&15 [m89/m91 verified]
// ---------------------------------------------------------------------------
template<int DT>
__device__ __forceinline__ void gemm_body(const void* X, const u16* __restrict__ WtT,
                                          u16* __restrict__ Pb,
                                          float* __restrict__ sumx2p) {
    const int t = threadIdx.x;
    const int w = t >> 6, l = t & 63;
    const int m = l & 15, q = l >> 4;
    const int tok0 = blockIdx.x * 64 + w * 16;
    const int p = blockIdx.y;
    const int k0 = p * KR;

    const size_t aoff = (size_t)(tok0 + m) * D + k0 + q * 8;
    const u16* bp = WtT + (size_t)m * D + k0 + q * 8;

    f32x4 acc[9];
#pragma unroll
    for (int ct = 0; ct < 9; ct++) acc[ct] = (f32x4){0.f, 0.f, 0.f, 0.f};
    float s2 = 0.f;

#pragma unroll
    for (int ks = 0; ks < KR / 32; ks++) {
        sh8 a = IO<DT>::afrag(X, aoff + ks * 32);
        sh8 b[9];
#pragma unroll
        for (int ct = 0; ct < 9; ct++)
            b[ct] = *(const sh8*)(bp + (size_t)ct * 16 * D + ks * 32);
#pragma unroll
        for (int i = 0; i < 8; i++) {
            float xv = bf2f((u16)a[i]);
            s2 = fmaf(xv, xv, s2);
        }
#pragma unroll
        for (int ct = 0; ct < 9; ct++)
            acc[ct] = __builtin_amdgcn_mfma_f32_16x16x32_bf16(a, b[ct], acc[ct], 0, 0, 0);
    }

    // Σx² over this K-slice: reduce over q (lanes m,m+16,m+32,m+48), store
    s2 += __shfl_xor(s2, 16, 64);
    s2 += __shfl_xor(s2, 32, 64);
    if (l < 16) sumx2p[(size_t)p * BT + tok0 + l] = s2;

    u16* Ps = Pb + (size_t)p * BT * NCOL;
#pragma unroll
    for (int ct = 0; ct < 9; ct++)
#pragma unroll
        for (int r = 0; r < 4; r++)
            Ps[(size_t)(tok0 + q * 4 + r) * NCOL + ct * 16 + m] = f2bf(acc[ct][r]);
}
__global__ __launch_bounds__(256) void k_gemm(const void* X, const u16* WtT,
                                              u16* Pb, float* sumx2p) {
    if (detect_fp32(X)) gemm_body<1>(X, WtT, Pb, sumx2p);
    else                gemm_body<0>(X, WtT, Pb, sumx2p);
}

// ---------------------------------------------------------------------------
// gate_wave: one wave computes one token's gate. 16 slices x 8 concepts
// mapped to 64 lanes (lane = p2*8+n handles slices 2p2,2p2+1 for concept n);
// xor-shuffle reductions; butterfly argmax over lanes 0..7 (first-max
// tie-break == np.argmax). Valid outputs: sval/c on all lanes, mx on l<8.
// ---------------------------------------------------------------------------
template<int DT>
__device__ __forceinline__ void gate_wave(
    const u16* __restrict__ Pb, const float* __restrict__ sumx2p,
    int tok, int l, const void* CENTER, const void* SLOPE,
    const float* __restrict__ OFF, const float* __restrict__ MU2,
    const float* __restrict__ UB,
    float* sval_out, int* c_out, float* mx_out) {
    const int n = l & 7, p2 = l >> 3;
    float pa[8] = {};
    float mdot = 0.f;
#pragma unroll
    for (int pp = 0; pp < 2; pp++) {
        const u16* pr = Pb + ((size_t)(2 * p2 + pp) * BT + tok) * NCOL;
        bf16x8 v = *(const bf16x8*)(pr + 8 * n);
#pragma unroll
        for (int k = 0; k < 8; k++) pa[k] += bf2f(v[k]);
        mdot += bf2f(pr[128 + n]);
    }
#pragma unroll
    for (int i = 8; i < 64; i <<= 1) {
#pragma unroll
        for (int k = 0; k < 8; k++) pa[k] += __shfl_xor(pa[k], i, 64);
        mdot += __shfl_xor(mdot, i, 64);
    }
    float s2 = sumx2p[(size_t)(l & 15) * BT + tok];
#pragma unroll
    for (int i = 1; i < 16; i <<= 1) s2 += __shfl_xor(s2, i, 64);

    float zv = -1e30f; int iv = n;
    if (l < 8) {
        float norm2 = s2 - 2.f * mdot + MU2[n];
        float sc = 0.f;
#pragma unroll
        for (int s = 0; s < 8; s++) {
            float dg = pa[s] - OFF[8 * n + s];
            sc += dg * dg;
        }
        sc /= norm2;
        zv = IO<DT>::ld1(SLOPE, n) * (sc - IO<DT>::ld1(CENTER, n));
    }
#pragma unroll
    for (int i = 1; i < 8; i <<= 1) {
        float z2 = __shfl_xor(zv, i, 64);
        int   i2 = __shfl_xor(iv, i, 64);
        if (z2 > zv || (z2 == zv && i2 < iv)) { zv = z2; iv = i2; }
    }
    const int c = __shfl(iv, 0, 64);
    const float zbest = __shfl(zv, 0, 64);

    float mxv = 0.f;
#pragma unroll
    for (int pp = 0; pp < 2; pp++)
        mxv += bf2f(Pb[((size_t)(2 * p2 + pp) * BT + tok) * NCOL + 64 + 8 * c + n]);
#pragma unroll
    for (int i = 8; i < 64; i <<= 1) mxv += __shfl_xor(mxv, i, 64);

    *sval_out = 1.f / (1.f + expf(-zbest));
    *c_out = c;
    *mx_out = mxv - UB[c * 8 + n];   // valid on lanes 0..7
}

// ---------------------------------------------------------------------------
// k_gate (fallback only, when slices must live in d_out): wave-per-token.
// ---------------------------------------------------------------------------
template<int DT>
__device__ __forceinline__ void kgate_body(
    const u16* Pb, const float* sumx2p, const void* CENTER, const void* SLOPE,
    const float* OFF, const float* MU2, const float* UB,
    float* svals, int* cs, float* mxs) {
    const int w = threadIdx.x >> 6, l = threadIdx.x & 63;
    const int tok = blockIdx.x * 4 + w;
    float sval, mxv; int c;
    gate_wave<DT>(Pb, sumx2p, tok, l, CENTER, SLOPE, OFF, MU2, UB, &sval, &c, &mxv);
    if (l < 8) mxs[(size_t)tok * 8 + l] = mxv;
    if (l == 0) { svals[tok] = sval; cs[tok] = c; }
}
__global__ __launch_bounds__(256) void k_gate(
    const void* X, const u16* Pb, const float* sumx2p,
    const void* CENTER, const void* SLOPE,
    const float* OFF, const float* MU2, const float* UB,
    float* svals, int* cs, float* mxs) {
    if (detect_fp32(X)) kgate_body<1>(Pb, sumx2p, CENTER, SLOPE, OFF, MU2, UB, svals, cs, mxs);
    else                kgate_body<0>(Pb, sumx2p, CENTER, SLOPE, OFF, MU2, UB, svals, cs, mxs);
}

// ---------------------------------------------------------------------------
// k_blend: block = token (256 threads, thread = 8 d's in two 4-chunks).
// fused=1: wave 0 computes the gate inline (slices in ws -> no race with
// the fp32 output write). fused=0: reads precomputed gate from ws.
// X loads issue before the barrier; coalesced BIAS/DGN(bf16)/OUT after.
// ---------------------------------------------------------------------------
template<int DT>
__device__ __forceinline__ void blend_body(
    const void* X, const u16* __restrict__ Pb, const float* __restrict__ sumx2p,
    const void* CENTER, const void* SLOPE,
    const float* __restrict__ OFF, const float* __restrict__ MU2,
    const float* __restrict__ UB,
    const float* __restrict__ svals, const int* __restrict__ cs,
    const float* __restrict__ mxs,
    const u16* __restrict__ DGNB, const void* BIAS, void* OUT, int fused) {
    const int tok = blockIdx.x;
    const int t = threadIdx.x, w = t >> 6, l = t & 63;
    __shared__ float sm[10];
    __shared__ int smc;

    float xf0[4], xf1[4];
    IO<DT>::ld4(X, (size_t)tok * D + t * 4, xf0);
    IO<DT>::ld4(X, (size_t)tok * D + 1024 + t * 4, xf1);

    if (w == 0) {
        float sval, mxv; int c;
        if (fused) {
            gate_wave<DT>(Pb, sumx2p, tok, l, CENTER, SLOPE, OFF, MU2, UB,
                          &sval, &c, &mxv);
        } else {
            sval = svals[tok]; c = cs[tok];
            mxv = (l < 8) ? mxs[(size_t)tok * 8 + l] : 0.f;
        }
        if (l < 8) sm[2 + l] = mxv;
        if (l == 0) { sm[0] = sval; smc = c; }
    }
    __syncthreads();

    const float sval = sm[0];
    const int c = smc;
    float mx[8];
#pragma unroll
    for (int h = 0; h < 8; h++) mx[h] = sm[2 + h];

#pragma unroll
    for (int half = 0; half < 2; half++) {
        const int d0 = half * 1024 + t * 4;
        const float* xf = half ? xf1 : xf0;
        float bv[4], ov[4];
        IO<DT>::ld4(BIAS, (size_t)c * D + d0, bv);
#pragma unroll
        for (int i = 0; i < 4; i++) {
            bf16x8 v = *(const bf16x8*)(DGNB + ((size_t)c * D + d0 + i) * 8);
            float du = bf2f(v[0]) * mx[0] + bf2f(v[1]) * mx[1]
                     + bf2f(v[2]) * mx[2] + bf2f(v[3]) * mx[3]
                     + bf2f(v[4]) * mx[4] + bf2f(v[5]) * mx[5]
                     + bf2f(v[6]) * mx[6] + bf2f(v[7]) * mx[7];
            ov[i] = (1.f - sval) * xf[i] + sval * (bv[i] + du);   // ETA = 1.0
        }
        IO<DT>::st4(OUT, (size_t)tok * D + d0, ov);
    }
}
__global__ __launch_bounds__(256) void k_blend(
    const void* X, const u16* Pb, const float* sumx2p,
    const void* CENTER, const void* SLOPE,
    const float* OFF, const float* MU2, const float* UB,
    const float* svals, const int* cs, const float* mxs,
    const u16* DGNB, const void* BIAS, void* OUT, int fused) {
    if (detect_fp32(X))
        blend_body<1>(X, Pb, sumx2p, CENTER, SLOPE, OFF, MU2, UB,
                      svals, cs, mxs, DGNB, BIAS, OUT, fused);
    else
        blend_body<0>(X, Pb, sumx2p, CENTER, SLOPE, OFF, MU2, UB,
                      svals, cs, mxs, DGNB, BIAS, OUT, fused);
}

// ---------------------------------------------------------------------------
extern "C" void kernel_launch(void* const* d_in, const int* in_sizes, int n_in,
                              void* d_out, int out_size, void* d_ws, size_t ws_size,
                              hipStream_t stream) {
    const void* x      = d_in[0];
    const void* selW   = d_in[1];
    const void* mu     = d_in[2];
    const void* center = d_in[3];
    const void* slope  = d_in[4];
    const void* upd    = d_in[5];
    const void* dgn    = d_in[6];
    const void* biasW  = d_in[7];
    const void* debW   = d_in[8];

    // ws layout (R7 PMC showed the harness poison-fills 256 MiB -> ws_size
    // is 256 MiB; fused path needs ~20.2 MB, fallback keeps slices in d_out)
    const size_t o_sumx2 = 0;                      // 262,144 B
    const size_t o_wtt   = 262144;                 // 589,824 B
    const size_t o_dgnb  = o_wtt + 589824;         // 262,144 B
    const size_t o_const = o_dgnb + 262144;        //     576 B (pad to 1 KB)
    const size_t o_sv    = o_const + 1024;         //  16,384 B
    const size_t o_cs    = o_sv + 16384;           //  16,384 B
    const size_t o_mxs   = o_cs + 16384;           // 131,072 B
    const size_t o_pb    = o_mxs + 131072;         // 18,874,368 B (bf16 slices)
    const size_t need    = o_pb + (size_t)KSPLIT * BT * NCOL * 2;

    char* ws = (char*)d_ws;
    float* sumx2p = (float*)(ws + o_sumx2);
    u16*   WtT    = (u16*)(ws + o_wtt);
    u16*   dgnb   = (u16*)(ws + o_dgnb);
    float* consts = (float*)(ws + o_const);
    float* svals  = (float*)(ws + o_sv);
    int*   cs     = (int*)(ws + o_cs);
    float* mxs    = (float*)(ws + o_mxs);
    float* off = consts;
    float* mu2 = consts + 64;
    float* ub  = consts + 72;

    const int fused = (ws_size >= need) ? 1 : 0;
    u16* Pb = fused ? (u16*)(ws + o_pb) : (u16*)d_out;   // fallback: slices in d_out

    k_prep<<<216, 256, 0, stream>>>(x, selW, upd, mu, debW, dgn,
                                    WtT, off, mu2, ub, dgnb);
    k_gemm<<<dim3(BT / 64, KSPLIT), 256, 0, stream>>>(x, WtT, Pb, sumx2p);
    if (!fused)
        k_gate<<<BT / 4, 256, 0, stream>>>(x, Pb, sumx2p, center, slope,
                                           off, mu2, ub, svals, cs, mxs);
    k_blend<<<BT, 256, 0, stream>>>(x, Pb, sumx2p, center, slope,
                                    off, mu2, ub, svals, cs, mxs,
                                    dgnb, biasW, d_out, fused);
}